// Round 1
// baseline (649.073 us; speedup 1.0000x reference)
//
#include <hip/hip_runtime.h>

// ---------------------------------------------------------------------------
// Transformer block (post-LN) on MI355X. Round 0: correctness-first MFMA.
//   x:[2,2048,1024] f32. All GEMMs in bf16 MFMA (16x16x32), fp32 accum.
//   Layout trick: all weights pre-transposed to W^T[N][K] bf16 so both A and
//   B fragments are contiguous 16B loads per lane.
// ---------------------------------------------------------------------------

typedef __attribute__((ext_vector_type(8))) short bf16x8;
typedef __attribute__((ext_vector_type(4))) float f32x4;
typedef __attribute__((ext_vector_type(4))) short short4v;

__device__ inline short f2bf(float f) {
    union { float f; unsigned u; } in{f};
    unsigned u = in.u;
    unsigned r = (u + 0x7fffu + ((u >> 16) & 1u)) >> 16;
    return (short)r;
}

// ---------------- prep kernels ----------------

__global__ __launch_bounds__(256) void convert_f2b(const float* __restrict__ in,
                                                   short* __restrict__ out, int n4) {
    int i = blockIdx.x * 256 + threadIdx.x;
    if (i < n4) {
        float4 v = *(const float4*)(in + (size_t)i * 4);
        short4v o = { f2bf(v.x), f2bf(v.y), f2bf(v.z), f2bf(v.w) };
        *(short4v*)(out + (size_t)i * 4) = o;
    }
}

// out[c][r] = bf16(in[r][c]); grid (C/32, R/32), block (32,8)
__global__ __launch_bounds__(256) void transpose_f2b(const float* __restrict__ in,
                                                     short* __restrict__ out, int R, int C) {
    __shared__ short tile[32][33];
    int c0 = blockIdx.x * 32, r0 = blockIdx.y * 32;
    int tx = threadIdx.x, ty = threadIdx.y;
    for (int i = ty; i < 32; i += 8)
        tile[i][tx] = f2bf(in[(size_t)(r0 + i) * C + c0 + tx]);
    __syncthreads();
    for (int i = ty; i < 32; i += 8)
        out[(size_t)(c0 + i) * R + r0 + tx] = tile[tx][i];
}

// bf16->bf16 transpose with input row stride
__global__ __launch_bounds__(256) void transpose_b2b(const short* __restrict__ in,
                                                     short* __restrict__ out, int R, int C,
                                                     int istride) {
    __shared__ short tile[32][33];
    int c0 = blockIdx.x * 32, r0 = blockIdx.y * 32;
    int tx = threadIdx.x, ty = threadIdx.y;
    for (int i = ty; i < 32; i += 8)
        tile[i][tx] = in[(size_t)(r0 + i) * istride + c0 + tx];
    __syncthreads();
    for (int i = ty; i < 32; i += 8)
        out[(size_t)(c0 + i) * R + r0 + tx] = tile[tx][i];
}

// ---------------- GEMM: C[M][N] = A[M][K] @ BT[N][K]^T (+bias, relu, bf16 out) ----
// block 128x128, 4 waves 2x2 of 64x64, frags 4x4 of 16x16x32.
template <int BIAS, int RELU, int OUTBF>
__global__ __launch_bounds__(256) void gemm_bt(const short* __restrict__ A,
                                               const short* __restrict__ BT,
                                               const float* __restrict__ bias,
                                               void* __restrict__ Cout,
                                               int M, int N, int K) {
    const int tid = threadIdx.x;
    const int wid = tid >> 6;
    const int lane = tid & 63;
    const int wr = wid >> 1, wc = wid & 1;
    const int row0 = blockIdx.x * 128 + wr * 64;
    const int col0 = blockIdx.y * 128 + wc * 64;
    const int lr = lane & 15;
    const int lk = (lane >> 4) * 8;

    f32x4 acc[4][4] = {};
    for (int k = 0; k < K; k += 32) {
        bf16x8 a[4], b[4];
#pragma unroll
        for (int m = 0; m < 4; ++m)
            a[m] = *(const bf16x8*)(A + (size_t)(row0 + m * 16 + lr) * K + k + lk);
#pragma unroll
        for (int n = 0; n < 4; ++n)
            b[n] = *(const bf16x8*)(BT + (size_t)(col0 + n * 16 + lr) * K + k + lk);
#pragma unroll
        for (int m = 0; m < 4; ++m)
#pragma unroll
            for (int n = 0; n < 4; ++n)
                acc[m][n] = __builtin_amdgcn_mfma_f32_16x16x32_bf16(a[m], b[n], acc[m][n], 0, 0, 0);
    }
#pragma unroll
    for (int m = 0; m < 4; ++m) {
        int row = row0 + m * 16 + (lane >> 4) * 4;
#pragma unroll
        for (int n = 0; n < 4; ++n) {
            int col = col0 + n * 16 + lr;
            float bv = BIAS ? bias[col] : 0.0f;
#pragma unroll
            for (int r = 0; r < 4; ++r) {
                float v = acc[m][n][r] + bv;
                if (RELU) v = fmaxf(v, 0.0f);
                if (OUTBF)
                    ((short*)Cout)[(size_t)(row + r) * N + col] = f2bf(v);
                else
                    ((float*)Cout)[(size_t)(row + r) * N + col] = v;
            }
        }
    }
}

// ---------------- flash attention ----------------
// Q,K from fused QKV buffer (row stride 3072), Vt [1024][4096], out attn bf16 [4096][1024].
// grid (T/64=32, B*H=32), block 256 (4 waves, 16 q-rows each). KV-block 32.
#define ATT_T 2048
#define ATT_QKS 3072
#define ATT_BT 4096

__global__ __launch_bounds__(256) void flash_attn(const short* __restrict__ Q,
                                                  const short* __restrict__ Km,
                                                  const short* __restrict__ Vt,
                                                  short* __restrict__ Oout) {
    const int b = blockIdx.y >> 4;
    const int h = blockIdx.y & 15;
    const int wid = threadIdx.x >> 6;
    const int lane = threadIdx.x & 63;
    const int q_base = blockIdx.x * 64 + wid * 16;
    const int lr = lane & 15;
    const int lkg = lane >> 4;  // 0..3

    __shared__ short Plds[4][16][40];  // per-wave P tile, padded (80B rows, 16B-aligned)

    // Q fragments (held in regs for whole kv loop)
    bf16x8 aq[2];
#pragma unroll
    for (int ds = 0; ds < 2; ++ds)
        aq[ds] = *(const bf16x8*)(Q + (size_t)(b * ATT_T + q_base + lr) * ATT_QKS + h * 64 + ds * 32 + lkg * 8);

    f32x4 O[4] = {};
    float mrun[4], lrun[4];
#pragma unroll
    for (int r = 0; r < 4; ++r) { mrun[r] = -1e30f; lrun[r] = 0.0f; }

    const int nkv = ((q_base + 15) >> 5) + 1;
    for (int kb = 0; kb < nkv; ++kb) {
        const int k0 = kb * 32;
        // S tiles: s[t] covers keys k0+t*16 .. +15
        f32x4 s0 = {}, s1 = {};
        {
            bf16x8 b0 = *(const bf16x8*)(Km + (size_t)(b * ATT_T + k0 + lr) * ATT_QKS + h * 64 + lkg * 8);
            bf16x8 b1 = *(const bf16x8*)(Km + (size_t)(b * ATT_T + k0 + lr) * ATT_QKS + h * 64 + 32 + lkg * 8);
            s0 = __builtin_amdgcn_mfma_f32_16x16x32_bf16(aq[0], b0, s0, 0, 0, 0);
            s0 = __builtin_amdgcn_mfma_f32_16x16x32_bf16(aq[1], b1, s0, 0, 0, 0);
            bf16x8 c0 = *(const bf16x8*)(Km + (size_t)(b * ATT_T + k0 + 16 + lr) * ATT_QKS + h * 64 + lkg * 8);
            bf16x8 c1 = *(const bf16x8*)(Km + (size_t)(b * ATT_T + k0 + 16 + lr) * ATT_QKS + h * 64 + 32 + lkg * 8);
            s1 = __builtin_amdgcn_mfma_f32_16x16x32_bf16(aq[0], c0, s1, 0, 0, 0);
            s1 = __builtin_amdgcn_mfma_f32_16x16x32_bf16(aq[1], c1, s1, 0, 0, 0);
        }
        // scale + causal mask + online softmax. row = q_base + lkg*4 + r, key = k0 + {lr, 16+lr}
#pragma unroll
        for (int r = 0; r < 4; ++r) {
            const int qrow = q_base + lkg * 4 + r;
            float v0 = s0[r] * 0.125f;
            float v1 = s1[r] * 0.125f;
            if (k0 + lr > qrow) v0 = -1e30f;
            if (k0 + 16 + lr > qrow) v1 = -1e30f;
            float mx = fmaxf(v0, v1);
            mx = fmaxf(mx, __shfl_xor(mx, 1));
            mx = fmaxf(mx, __shfl_xor(mx, 2));
            mx = fmaxf(mx, __shfl_xor(mx, 4));
            mx = fmaxf(mx, __shfl_xor(mx, 8));
            float mnew = fmaxf(mrun[r], mx);
            float alpha = __expf(mrun[r] - mnew);
            mrun[r] = mnew;
            float p0 = __expf(v0 - mnew);
            float p1 = __expf(v1 - mnew);
            float rs = p0 + p1;
            rs += __shfl_xor(rs, 1);
            rs += __shfl_xor(rs, 2);
            rs += __shfl_xor(rs, 4);
            rs += __shfl_xor(rs, 8);
            lrun[r] = lrun[r] * alpha + rs;
#pragma unroll
            for (int n = 0; n < 4; ++n) O[n][r] *= alpha;
            Plds[wid][lkg * 4 + r][lr] = f2bf(p0);
            Plds[wid][lkg * 4 + r][16 + lr] = f2bf(p1);
        }
        asm volatile("s_waitcnt lgkmcnt(0)" ::: "memory");
        // P A-frag: lane holds P[q=lr][key=lkg*8 + j]
        bf16x8 ap = *(const bf16x8*)(&Plds[wid][lr][lkg * 8]);
#pragma unroll
        for (int n = 0; n < 4; ++n) {
            bf16x8 bv = *(const bf16x8*)(Vt + (size_t)(h * 64 + n * 16 + lr) * ATT_BT + b * ATT_T + k0 + lkg * 8);
            O[n] = __builtin_amdgcn_mfma_f32_16x16x32_bf16(ap, bv, O[n], 0, 0, 0);
        }
        asm volatile("s_waitcnt lgkmcnt(0)" ::: "memory");
    }
    // write out: row = q_base + lkg*4 + r, col = h*64 + n*16 + lr
    float inv[4];
#pragma unroll
    for (int r = 0; r < 4; ++r) inv[r] = 1.0f / lrun[r];
#pragma unroll
    for (int n = 0; n < 4; ++n)
#pragma unroll
        for (int r = 0; r < 4; ++r)
            Oout[(size_t)(b * ATT_T + q_base + lkg * 4 + r) * 1024 + h * 64 + n * 16 + lr] =
                f2bf(O[n][r] * inv[r]);
}

// ---------------- residual + layernorm ----------------
// h = x + y; out = (h-mu)*rstd*g + be. One block per row (1024 cols, 256 thr x float4).
__global__ __launch_bounds__(256) void resid_ln(const float* __restrict__ x,
                                                const float* __restrict__ y,
                                                const float* __restrict__ g,
                                                const float* __restrict__ be,
                                                float* __restrict__ of,
                                                short* __restrict__ ob) {
    const int row = blockIdx.x;
    const int tid = threadIdx.x;
    const size_t base = (size_t)row * 1024 + tid * 4;
    float4 xv = *(const float4*)(x + base);
    float4 yv = *(const float4*)(y + base);
    float h0 = xv.x + yv.x, h1 = xv.y + yv.y, h2 = xv.z + yv.z, h3 = xv.w + yv.w;
    float s = h0 + h1 + h2 + h3;
    float ss = h0 * h0 + h1 * h1 + h2 * h2 + h3 * h3;
#pragma unroll
    for (int d = 1; d < 64; d <<= 1) {
        s += __shfl_xor(s, d);
        ss += __shfl_xor(ss, d);
    }
    __shared__ float as_[4], ass_[4];
    if ((tid & 63) == 0) { as_[tid >> 6] = s; ass_[tid >> 6] = ss; }
    __syncthreads();
    s = as_[0] + as_[1] + as_[2] + as_[3];
    ss = ass_[0] + ass_[1] + ass_[2] + ass_[3];
    const float mu = s * (1.0f / 1024.0f);
    const float var = ss * (1.0f / 1024.0f) - mu * mu;
    const float rstd = rsqrtf(var + 1e-5f);
    float4 gv = *(const float4*)(g + tid * 4);
    float4 bv = *(const float4*)(be + tid * 4);
    float o0 = (h0 - mu) * rstd * gv.x + bv.x;
    float o1 = (h1 - mu) * rstd * gv.y + bv.y;
    float o2 = (h2 - mu) * rstd * gv.z + bv.z;
    float o3 = (h3 - mu) * rstd * gv.w + bv.w;
    float4 ov = { o0, o1, o2, o3 };
    *(float4*)(of + base) = ov;
    if (ob) {
        short4v obv = { f2bf(o0), f2bf(o1), f2bf(o2), f2bf(o3) };
        *(short4v*)(ob + base) = obv;
    }
}

// ---------------- launch ----------------

extern "C" void kernel_launch(void* const* d_in, const int* in_sizes, int n_in,
                              void* d_out, int out_size, void* d_ws, size_t ws_size,
                              hipStream_t stream) {
    const float* x = (const float*)d_in[0];
    const float* wq = (const float*)d_in[1];
    const float* wk = (const float*)d_in[2];
    const float* wv = (const float*)d_in[3];
    const float* wp = (const float*)d_in[4];
    const float* bproj = (const float*)d_in[5];
    const float* w1 = (const float*)d_in[6];
    const float* b1 = (const float*)d_in[7];
    const float* w2 = (const float*)d_in[8];
    const float* b2 = (const float*)d_in[9];
    const float* g1 = (const float*)d_in[10];
    const float* be1 = (const float*)d_in[11];
    const float* g2 = (const float*)d_in[12];
    const float* be2 = (const float*)d_in[13];

    char* ws = (char*)d_ws;
    const size_t MB = 1024 * 1024;
    short* x_bf = (short*)(ws + 0);        // 8 MB  [4096][1024]
    short* wqkvT = (short*)(ws + 8 * MB);  // 6 MB  [3072][1024] (wqT|wkT|wvT)
    short* wqT = wqkvT;
    short* wkT = (short*)(ws + 10 * MB);
    short* wvT = (short*)(ws + 12 * MB);
    short* wpT = (short*)(ws + 14 * MB);   // 2 MB
    short* w1T = (short*)(ws + 16 * MB);   // 8 MB  [4096][1024]
    short* w2T = (short*)(ws + 24 * MB);   // 8 MB  [1024][4096]
    short* qkv = (short*)(ws + 32 * MB);   // 24 MB [4096][3072]
    short* Vt  = (short*)(ws + 56 * MB);   // 8 MB  [1024][4096]
    short* hbf = (short*)(ws + 32 * MB);   // 32 MB [4096][4096] (reuses qkv+Vt)
    short* attn = (short*)(ws + 64 * MB);  // 8 MB  [4096][1024]
    short* x1bf = (short*)(ws + 64 * MB);  // 8 MB  (reuses attn)
    float* y1 = (float*)(ws + 72 * MB);    // 16 MB [4096][1024]
    float* y2 = (float*)(ws + 72 * MB);    // 16 MB (reuses y1)
    float* x1f = (float*)(ws + 88 * MB);   // 16 MB
    // total 104 MB

    dim3 blk(256);
    dim3 tb(32, 8);

    convert_f2b<<<dim3(4096), blk, 0, stream>>>(x, x_bf, 4096 * 1024 / 4);
    transpose_f2b<<<dim3(32, 32), tb, 0, stream>>>(wq, wqT, 1024, 1024);
    transpose_f2b<<<dim3(32, 32), tb, 0, stream>>>(wk, wkT, 1024, 1024);
    transpose_f2b<<<dim3(32, 32), tb, 0, stream>>>(wv, wvT, 1024, 1024);
    transpose_f2b<<<dim3(32, 32), tb, 0, stream>>>(wp, wpT, 1024, 1024);
    transpose_f2b<<<dim3(128, 32), tb, 0, stream>>>(w1, w1T, 1024, 4096);
    transpose_f2b<<<dim3(32, 128), tb, 0, stream>>>(w2, w2T, 4096, 1024);

    // QKV fused GEMM: [4096,1024] @ [1024,3072] -> [4096,3072] bf16
    gemm_bt<0, 0, 1><<<dim3(32, 24), blk, 0, stream>>>(x_bf, wqkvT, nullptr, qkv, 4096, 3072, 1024);
    // V^T for PV fragments
    transpose_b2b<<<dim3(32, 128), tb, 0, stream>>>(qkv + 2048, Vt, 4096, 1024, 3072);
    // attention
    flash_attn<<<dim3(32, 32), blk, 0, stream>>>(qkv, qkv + 1024, Vt, attn);
    // proj + bias -> f32
    gemm_bt<1, 0, 0><<<dim3(32, 8), blk, 0, stream>>>(attn, wpT, bproj, y1, 4096, 1024, 1024);
    // LN1 (residual with original x)
    resid_ln<<<dim3(4096), blk, 0, stream>>>(x, y1, g1, be1, x1f, x1bf);
    // MLP1 + bias + relu -> bf16
    gemm_bt<1, 1, 1><<<dim3(32, 32), blk, 0, stream>>>(x1bf, w1T, b1, hbf, 4096, 4096, 1024);
    // MLP2 + bias -> f32
    gemm_bt<1, 0, 0><<<dim3(32, 8), blk, 0, stream>>>(hbf, w2T, b2, y2, 4096, 1024, 4096);
    // LN2 -> d_out
    resid_ln<<<dim3(4096), blk, 0, stream>>>(x1f, y2, g2, be2, (float*)d_out, nullptr);
}

// Round 2
// 487.790 us; speedup vs baseline: 1.3306x; 1.3306x over previous
//
#include <hip/hip_runtime.h>

// ---------------------------------------------------------------------------
// Transformer block (post-LN) on MI355X. Round 1:
//  - GEMMs: 128x128 tile, global_load_lds width-16 staging (m97 structure).
//  - Attention: swapped QK^T (S^T = mfma(K,Q)) so softmax is in-lane;
//    KVBLK=64; PV as O^T = mfma(Vt, P).
// ---------------------------------------------------------------------------

typedef __attribute__((ext_vector_type(8))) short bf16x8;
typedef __attribute__((ext_vector_type(4))) float f32x4;
typedef __attribute__((ext_vector_type(4))) short short4v;

__device__ inline short f2bf(float f) {
    union { float f; unsigned u; } in{f};
    unsigned u = in.u;
    unsigned r = (u + 0x7fffu + ((u >> 16) & 1u)) >> 16;
    return (short)r;
}

// ---------------- prep kernels ----------------

__global__ __launch_bounds__(256) void convert_f2b(const float* __restrict__ in,
                                                   short* __restrict__ out, int n4) {
    int i = blockIdx.x * 256 + threadIdx.x;
    if (i < n4) {
        float4 v = *(const float4*)(in + (size_t)i * 4);
        short4v o = { f2bf(v.x), f2bf(v.y), f2bf(v.z), f2bf(v.w) };
        *(short4v*)(out + (size_t)i * 4) = o;
    }
}

// out[c][r] = bf16(in[r][c]); grid (C/32, R/32), block (32,8)
__global__ __launch_bounds__(256) void transpose_f2b(const float* __restrict__ in,
                                                     short* __restrict__ out, int R, int C) {
    __shared__ short tile[32][33];
    int c0 = blockIdx.x * 32, r0 = blockIdx.y * 32;
    int tx = threadIdx.x, ty = threadIdx.y;
    for (int i = ty; i < 32; i += 8)
        tile[i][tx] = f2bf(in[(size_t)(r0 + i) * C + c0 + tx]);
    __syncthreads();
    for (int i = ty; i < 32; i += 8)
        out[(size_t)(c0 + i) * R + r0 + tx] = tile[tx][i];
}

// bf16->bf16 transpose with input row stride
__global__ __launch_bounds__(256) void transpose_b2b(const short* __restrict__ in,
                                                     short* __restrict__ out, int R, int C,
                                                     int istride) {
    __shared__ short tile[32][33];
    int c0 = blockIdx.x * 32, r0 = blockIdx.y * 32;
    int tx = threadIdx.x, ty = threadIdx.y;
    for (int i = ty; i < 32; i += 8)
        tile[i][tx] = in[(size_t)(r0 + i) * istride + c0 + tx];
    __syncthreads();
    for (int i = ty; i < 32; i += 8)
        out[(size_t)(c0 + i) * R + r0 + tx] = tile[tx][i];
}

// ---------------- GEMM: C[M][N] = A[M][K] @ BT[N][K]^T ----------------
// 128x128 block, 4 waves 2x2 of 64x64, frags 4x4 of 16x16x32.
// A/B tiles staged to LDS via global_load_lds (16B/lane, linear dest).
template <int BIAS, int RELU, int OUTBF>
__global__ __launch_bounds__(256) void gemm_bt(const short* __restrict__ A,
                                               const short* __restrict__ BT,
                                               const float* __restrict__ bias,
                                               void* __restrict__ Cout,
                                               int M, int N, int K) {
    __shared__ short As[128 * 32];
    __shared__ short Bs[128 * 32];
    const int tid = threadIdx.x;
    const int wid = tid >> 6;
    const int lane = tid & 63;
    const int wr = wid >> 1, wc = wid & 1;
    const int row0 = blockIdx.x * 128;
    const int col0 = blockIdx.y * 128;
    const int lr = lane & 15;
    const int lk = (lane >> 4) * 8;
    const int sr = lane >> 2;        // staging row within 16-row chunk
    const int sc = (lane & 3) * 8;   // staging col (8 bf16 = 16B)

    f32x4 acc[4][4] = {};
    for (int k = 0; k < K; k += 32) {
#pragma unroll
        for (int c = 0; c < 2; ++c) {
            const int ch = wid + c * 4;  // 16-row chunk index 0..7
            const short* ga = A + (size_t)(row0 + ch * 16 + sr) * K + k + sc;
            const short* gb = BT + (size_t)(col0 + ch * 16 + sr) * K + k + sc;
            __builtin_amdgcn_global_load_lds(
                (const __attribute__((address_space(1))) unsigned int*)ga,
                (__attribute__((address_space(3))) unsigned int*)(As + ch * 512), 16, 0, 0);
            __builtin_amdgcn_global_load_lds(
                (const __attribute__((address_space(1))) unsigned int*)gb,
                (__attribute__((address_space(3))) unsigned int*)(Bs + ch * 512), 16, 0, 0);
        }
        __syncthreads();  // drains vmcnt -> LDS tiles valid
        bf16x8 a[4], b[4];
#pragma unroll
        for (int m = 0; m < 4; ++m)
            a[m] = *(const bf16x8*)(As + (wr * 64 + m * 16 + lr) * 32 + lk);
#pragma unroll
        for (int n = 0; n < 4; ++n)
            b[n] = *(const bf16x8*)(Bs + (wc * 64 + n * 16 + lr) * 32 + lk);
#pragma unroll
        for (int m = 0; m < 4; ++m)
#pragma unroll
            for (int n = 0; n < 4; ++n)
                acc[m][n] = __builtin_amdgcn_mfma_f32_16x16x32_bf16(a[m], b[n], acc[m][n], 0, 0, 0);
        __syncthreads();  // done reading before next overwrite
    }
#pragma unroll
    for (int m = 0; m < 4; ++m) {
        int row = row0 + wr * 64 + m * 16 + (lane >> 4) * 4;
#pragma unroll
        for (int n = 0; n < 4; ++n) {
            int col = col0 + wc * 64 + n * 16 + lr;
            float bv = BIAS ? bias[col] : 0.0f;
#pragma unroll
            for (int r = 0; r < 4; ++r) {
                float v = acc[m][n][r] + bv;
                if (RELU) v = fmaxf(v, 0.0f);
                if (OUTBF)
                    ((short*)Cout)[(size_t)(row + r) * N + col] = f2bf(v);
                else
                    ((float*)Cout)[(size_t)(row + r) * N + col] = v;
            }
        }
    }
}

// ---------------- flash attention (swapped QK^T) ----------------
// Q,K from fused QKV buffer (row stride 3072), Vt [1024][4096], out bf16 [4096][1024].
// grid (T/64=32, B*H=32), block 256 (4 waves, 16 q-rows each). KVBLK=64.
// S^T = mfma(K_frag, Q_frag): col=q=lane&15, rows=keys in regs -> in-lane softmax.
// O^T = mfma(Vt_frag, P_frag): col=q, rows=d in regs.
#define ATT_T 2048
#define ATT_QKS 3072
#define ATT_BT 4096

__global__ __launch_bounds__(256) void flash_attn(const short* __restrict__ Q,
                                                  const short* __restrict__ Km,
                                                  const short* __restrict__ Vt,
                                                  short* __restrict__ Oout) {
    const int b = blockIdx.y >> 4;
    const int h = blockIdx.y & 15;
    const int wid = threadIdx.x >> 6;
    const int lane = threadIdx.x & 63;
    const int q_base = blockIdx.x * 64 + wid * 16;
    const int lr = lane & 15;
    const int g = lane >> 4;  // 0..3

    __shared__ __align__(16) short Plds[4][16][72];  // [wave][q][key], 144B rows (16B-mult)

    // Q fragment (B-operand): row=q=lr, k-elems ds*32 + g*8
    bf16x8 aq[2];
#pragma unroll
    for (int ds = 0; ds < 2; ++ds)
        aq[ds] = *(const bf16x8*)(Q + (size_t)(b * ATT_T + q_base + lr) * ATT_QKS + h * 64 + ds * 32 + g * 8);

    f32x4 O[4] = {};  // O^T: d-subtile n, col=q=lr, rows d = n*16 + g*4 + r
    float mrun = -1e30f, lrun = 0.0f;
    const int qrow = q_base + lr;

    const int nkv = ((q_base + 15) >> 6) + 1;
    for (int kb = 0; kb < nkv; ++kb) {
        const int k0 = kb * 64;
        // S^T: 4 key-subtiles of 16; lane holds keys k0 + 16t + g*4 + r for q=lr
        f32x4 st[4];
#pragma unroll
        for (int t = 0; t < 4; ++t) {
            const size_t krow = (size_t)(b * ATT_T + k0 + 16 * t + lr) * ATT_QKS + h * 64;
            bf16x8 kf0 = *(const bf16x8*)(Km + krow + g * 8);
            bf16x8 kf1 = *(const bf16x8*)(Km + krow + 32 + g * 8);
            f32x4 s = {};
            s = __builtin_amdgcn_mfma_f32_16x16x32_bf16(kf0, aq[0], s, 0, 0, 0);
            s = __builtin_amdgcn_mfma_f32_16x16x32_bf16(kf1, aq[1], s, 0, 0, 0);
            st[t] = s;
        }
        // in-lane softmax over 16 p-values + 2 cross-group shuffles
        float v[4][4];
        float mx = -1e30f;
#pragma unroll
        for (int t = 0; t < 4; ++t)
#pragma unroll
            for (int r = 0; r < 4; ++r) {
                float val = st[t][r] * 0.125f;
                const int key = k0 + 16 * t + g * 4 + r;
                if (key > qrow) val = -1e30f;
                v[t][r] = val;
                mx = fmaxf(mx, val);
            }
        mx = fmaxf(mx, __shfl_xor(mx, 16));
        mx = fmaxf(mx, __shfl_xor(mx, 32));
        const float mnew = fmaxf(mrun, mx);
        const float alpha = __expf(mrun - mnew);
        mrun = mnew;
        float rs = 0.0f;
        short4v pw[4];
#pragma unroll
        for (int t = 0; t < 4; ++t)
#pragma unroll
            for (int r = 0; r < 4; ++r) {
                float p = __expf(v[t][r] - mnew);
                rs += p;
                pw[t][r] = f2bf(p);
            }
        rs += __shfl_xor(rs, 16);
        rs += __shfl_xor(rs, 32);
        lrun = lrun * alpha + rs;
#pragma unroll
        for (int n = 0; n < 4; ++n)
#pragma unroll
            for (int r = 0; r < 4; ++r) O[n][r] *= alpha;
        // P -> LDS: [q=lr][key] rows; lane writes 4 contiguous keys per subtile
#pragma unroll
        for (int t = 0; t < 4; ++t)
            *(short4v*)(&Plds[wid][lr][16 * t + g * 4]) = pw[t];
        asm volatile("s_waitcnt lgkmcnt(0)" ::: "memory");
        __builtin_amdgcn_sched_barrier(0);
        // PV: O^T += Vt_frag @ P_frag over 2 K-steps of 32 keys
#pragma unroll
        for (int ks = 0; ks < 2; ++ks) {
            bf16x8 pf = *(const bf16x8*)(&Plds[wid][lr][ks * 32 + g * 8]);
#pragma unroll
            for (int n = 0; n < 4; ++n) {
                bf16x8 vf = *(const bf16x8*)(Vt + (size_t)(h * 64 + n * 16 + lr) * ATT_BT +
                                             b * ATT_T + k0 + ks * 32 + g * 8);
                O[n] = __builtin_amdgcn_mfma_f32_16x16x32_bf16(vf, pf, O[n], 0, 0, 0);
            }
        }
        asm volatile("s_waitcnt lgkmcnt(0)" ::: "memory");
        __builtin_amdgcn_sched_barrier(0);
    }
    const float inv = 1.0f / lrun;
#pragma unroll
    for (int n = 0; n < 4; ++n) {
        short4v ov;
#pragma unroll
        for (int r = 0; r < 4; ++r) ov[r] = f2bf(O[n][r] * inv);
        *(short4v*)(Oout + (size_t)(b * ATT_T + q_base + lr) * 1024 + h * 64 + n * 16 + g * 4) = ov;
    }
}

// ---------------- residual + layernorm ----------------
__global__ __launch_bounds__(256) void resid_ln(const float* __restrict__ x,
                                                const float* __restrict__ y,
                                                const float* __restrict__ g,
                                                const float* __restrict__ be,
                                                float* __restrict__ of,
                                                short* __restrict__ ob) {
    const int row = blockIdx.x;
    const int tid = threadIdx.x;
    const size_t base = (size_t)row * 1024 + tid * 4;
    float4 xv = *(const float4*)(x + base);
    float4 yv = *(const float4*)(y + base);
    float h0 = xv.x + yv.x, h1 = xv.y + yv.y, h2 = xv.z + yv.z, h3 = xv.w + yv.w;
    float s = h0 + h1 + h2 + h3;
    float ss = h0 * h0 + h1 * h1 + h2 * h2 + h3 * h3;
#pragma unroll
    for (int d = 1; d < 64; d <<= 1) {
        s += __shfl_xor(s, d);
        ss += __shfl_xor(ss, d);
    }
    __shared__ float as_[4], ass_[4];
    if ((tid & 63) == 0) { as_[tid >> 6] = s; ass_[tid >> 6] = ss; }
    __syncthreads();
    s = as_[0] + as_[1] + as_[2] + as_[3];
    ss = ass_[0] + ass_[1] + ass_[2] + ass_[3];
    const float mu = s * (1.0f / 1024.0f);
    const float var = ss * (1.0f / 1024.0f) - mu * mu;
    const float rstd = rsqrtf(var + 1e-5f);
    float4 gv = *(const float4*)(g + tid * 4);
    float4 bv = *(const float4*)(be + tid * 4);
    float o0 = (h0 - mu) * rstd * gv.x + bv.x;
    float o1 = (h1 - mu) * rstd * gv.y + bv.y;
    float o2 = (h2 - mu) * rstd * gv.z + bv.z;
    float o3 = (h3 - mu) * rstd * gv.w + bv.w;
    float4 ov = { o0, o1, o2, o3 };
    *(float4*)(of + base) = ov;
    if (ob) {
        short4v obv = { f2bf(o0), f2bf(o1), f2bf(o2), f2bf(o3) };
        *(short4v*)(ob + base) = obv;
    }
}

// ---------------- launch ----------------

extern "C" void kernel_launch(void* const* d_in, const int* in_sizes, int n_in,
                              void* d_out, int out_size, void* d_ws, size_t ws_size,
                              hipStream_t stream) {
    const float* x = (const float*)d_in[0];
    const float* wq = (const float*)d_in[1];
    const float* wk = (const float*)d_in[2];
    const float* wv = (const float*)d_in[3];
    const float* wp = (const float*)d_in[4];
    const float* bproj = (const float*)d_in[5];
    const float* w1 = (const float*)d_in[6];
    const float* b1 = (const float*)d_in[7];
    const float* w2 = (const float*)d_in[8];
    const float* b2 = (const float*)d_in[9];
    const float* g1 = (const float*)d_in[10];
    const float* be1 = (const float*)d_in[11];
    const float* g2 = (const float*)d_in[12];
    const float* be2 = (const float*)d_in[13];

    char* ws = (char*)d_ws;
    const size_t MB = 1024 * 1024;
    short* x_bf = (short*)(ws + 0);        // 8 MB  [4096][1024]
    short* wqkvT = (short*)(ws + 8 * MB);  // 6 MB  [3072][1024] (wqT|wkT|wvT)
    short* wqT = wqkvT;
    short* wkT = (short*)(ws + 10 * MB);
    short* wvT = (short*)(ws + 12 * MB);
    short* wpT = (short*)(ws + 14 * MB);   // 2 MB
    short* w1T = (short*)(ws + 16 * MB);   // 8 MB  [4096][1024]
    short* w2T = (short*)(ws + 24 * MB);   // 8 MB  [1024][4096]
    short* qkv = (short*)(ws + 32 * MB);   // 24 MB [4096][3072]
    short* Vt  = (short*)(ws + 56 * MB);   // 8 MB  [1024][4096]
    short* hbf = (short*)(ws + 32 * MB);   // 32 MB [4096][4096] (reuses qkv+Vt)
    short* attn = (short*)(ws + 64 * MB);  // 8 MB  [4096][1024]
    short* x1bf = (short*)(ws + 64 * MB);  // 8 MB  (reuses attn)
    float* y1 = (float*)(ws + 72 * MB);    // 16 MB [4096][1024]
    float* y2 = (float*)(ws + 72 * MB);    // 16 MB (reuses y1)
    float* x1f = (float*)(ws + 88 * MB);   // 16 MB

    dim3 blk(256);
    dim3 tb(32, 8);

    convert_f2b<<<dim3(4096), blk, 0, stream>>>(x, x_bf, 4096 * 1024 / 4);
    transpose_f2b<<<dim3(32, 32), tb, 0, stream>>>(wq, wqT, 1024, 1024);
    transpose_f2b<<<dim3(32, 32), tb, 0, stream>>>(wk, wkT, 1024, 1024);
    transpose_f2b<<<dim3(32, 32), tb, 0, stream>>>(wv, wvT, 1024, 1024);
    transpose_f2b<<<dim3(32, 32), tb, 0, stream>>>(wp, wpT, 1024, 1024);
    transpose_f2b<<<dim3(128, 32), tb, 0, stream>>>(w1, w1T, 1024, 4096);
    transpose_f2b<<<dim3(32, 128), tb, 0, stream>>>(w2, w2T, 4096, 1024);

    gemm_bt<0, 0, 1><<<dim3(32, 24), blk, 0, stream>>>(x_bf, wqkvT, nullptr, qkv, 4096, 3072, 1024);
    transpose_b2b<<<dim3(32, 128), tb, 0, stream>>>(qkv + 2048, Vt, 4096, 1024, 3072);
    flash_attn<<<dim3(32, 32), blk, 0, stream>>>(qkv, qkv + 1024, Vt, attn);
    gemm_bt<1, 0, 0><<<dim3(32, 8), blk, 0, stream>>>(attn, wpT, bproj, y1, 4096, 1024, 1024);
    resid_ln<<<dim3(4096), blk, 0, stream>>>(x, y1, g1, be1, x1f, x1bf);
    gemm_bt<1, 1, 1><<<dim3(32, 32), blk, 0, stream>>>(x1bf, w1T, b1, hbf, 4096, 4096, 1024);
    gemm_bt<1, 0, 0><<<dim3(32, 8), blk, 0, stream>>>(hbf, w2T, b2, y2, 4096, 1024, 4096);
    resid_ln<<<dim3(4096), blk, 0, stream>>>(x1f, y2, g2, be2, (float*)d_out, nullptr);
}

// Round 3
// 366.709 us; speedup vs baseline: 1.7700x; 1.3302x over previous
//
#include <hip/hip_runtime.h>

// ---------------------------------------------------------------------------
// Transformer block (post-LN) on MI355X. Round 2:
//  - Attention: 32 q-rows/wave (2x16 subtiles, ILP), KVBLK=64, early V loads,
//    exp2-domain softmax, XCD-chunked + heavy-first block swizzle.
//  - GEMMs: m97 structure; BN=64 tiles for N=1024 GEMMs (2 blocks/CU);
//    XCD-chunked block swizzle on all GEMMs.
// ---------------------------------------------------------------------------

typedef __attribute__((ext_vector_type(8))) short bf16x8;
typedef __attribute__((ext_vector_type(4))) float f32x4;
typedef __attribute__((ext_vector_type(4))) short short4v;

__device__ inline short f2bf(float f) {
    union { float f; unsigned u; } in{f};
    unsigned u = in.u;
    unsigned r = (u + 0x7fffu + ((u >> 16) & 1u)) >> 16;
    return (short)r;
}

// ---------------- prep kernels ----------------

__global__ __launch_bounds__(256) void convert_f2b(const float* __restrict__ in,
                                                   short* __restrict__ out, int n4) {
    int i = blockIdx.x * 256 + threadIdx.x;
    if (i < n4) {
        float4 v = *(const float4*)(in + (size_t)i * 4);
        short4v o = { f2bf(v.x), f2bf(v.y), f2bf(v.z), f2bf(v.w) };
        *(short4v*)(out + (size_t)i * 4) = o;
    }
}

__global__ __launch_bounds__(256) void transpose_f2b(const float* __restrict__ in,
                                                     short* __restrict__ out, int R, int C) {
    __shared__ short tile[32][33];
    int c0 = blockIdx.x * 32, r0 = blockIdx.y * 32;
    int tx = threadIdx.x, ty = threadIdx.y;
    for (int i = ty; i < 32; i += 8)
        tile[i][tx] = f2bf(in[(size_t)(r0 + i) * C + c0 + tx]);
    __syncthreads();
    for (int i = ty; i < 32; i += 8)
        out[(size_t)(c0 + i) * R + r0 + tx] = tile[tx][i];
}

__global__ __launch_bounds__(256) void transpose_b2b(const short* __restrict__ in,
                                                     short* __restrict__ out, int R, int C,
                                                     int istride) {
    __shared__ short tile[32][33];
    int c0 = blockIdx.x * 32, r0 = blockIdx.y * 32;
    int tx = threadIdx.x, ty = threadIdx.y;
    for (int i = ty; i < 32; i += 8)
        tile[i][tx] = in[(size_t)(r0 + i) * istride + c0 + tx];
    __syncthreads();
    for (int i = ty; i < 32; i += 8)
        out[(size_t)(c0 + i) * R + r0 + tx] = tile[tx][i];
}

// ---------------- GEMM: C[M][N] = A[M][K] @ BT[N][K]^T ----------------
// 128 x BN block, 4 waves 2x2; BN=128 -> 64x64/wave (4x4 frags);
// BN=64 -> 64x32/wave (4x2 frags). global_load_lds 16B staging, BK=32.
template <int BN, int BIAS, int RELU, int OUTBF>
__global__ __launch_bounds__(256) void gemm_bt(const short* __restrict__ A,
                                               const short* __restrict__ BT,
                                               const float* __restrict__ bias,
                                               void* __restrict__ Cout,
                                               int M, int N, int K) {
    constexpr int NI = BN / 32;  // b-frags per wave
    __shared__ short As[128 * 32];
    __shared__ short Bs[BN * 32];
    const int tid = threadIdx.x;
    const int wid = tid >> 6;
    const int lane = tid & 63;
    const int wr = wid >> 1, wc = wid & 1;
    // XCD-chunked bijective swizzle (requires nwg % 8 == 0; all our grids are)
    const int gx = gridDim.x;
    int flat = blockIdx.x + gx * blockIdx.y;
    const int nwg = gx * gridDim.y;
    int w = flat;
    if ((nwg & 7) == 0) {
        const int q = nwg >> 3;
        w = (flat & 7) * q + (flat >> 3);
    }
    const int row0 = (w % gx) * 128;
    const int col0 = (w / gx) * BN;
    const int lr = lane & 15;
    const int lk = (lane >> 4) * 8;
    const int sr = lane >> 2;
    const int sc = (lane & 3) * 8;

    f32x4 acc[4][NI] = {};
    for (int k = 0; k < K; k += 32) {
#pragma unroll
        for (int c = 0; c < 2; ++c) {
            const int ch = wid + c * 4;
            const short* ga = A + (size_t)(row0 + ch * 16 + sr) * K + k + sc;
            __builtin_amdgcn_global_load_lds(
                (const __attribute__((address_space(1))) unsigned int*)ga,
                (__attribute__((address_space(3))) unsigned int*)(As + ch * 512), 16, 0, 0);
        }
#pragma unroll
        for (int c = 0; c < BN / 64; ++c) {
            const int ch = wid + c * 4;
            const short* gb = BT + (size_t)(col0 + ch * 16 + sr) * K + k + sc;
            __builtin_amdgcn_global_load_lds(
                (const __attribute__((address_space(1))) unsigned int*)gb,
                (__attribute__((address_space(3))) unsigned int*)(Bs + ch * 512), 16, 0, 0);
        }
        __syncthreads();
        bf16x8 a[4], b[NI];
#pragma unroll
        for (int m = 0; m < 4; ++m)
            a[m] = *(const bf16x8*)(As + (wr * 64 + m * 16 + lr) * 32 + lk);
#pragma unroll
        for (int n = 0; n < NI; ++n)
            b[n] = *(const bf16x8*)(Bs + (wc * (BN / 2) + n * 16 + lr) * 32 + lk);
#pragma unroll
        for (int m = 0; m < 4; ++m)
#pragma unroll
            for (int n = 0; n < NI; ++n)
                acc[m][n] = __builtin_amdgcn_mfma_f32_16x16x32_bf16(a[m], b[n], acc[m][n], 0, 0, 0);
        __syncthreads();
    }
#pragma unroll
    for (int m = 0; m < 4; ++m) {
        int row = row0 + wr * 64 + m * 16 + (lane >> 4) * 4;
#pragma unroll
        for (int n = 0; n < NI; ++n) {
            int col = col0 + wc * (BN / 2) + n * 16 + lr;
            float bv = BIAS ? bias[col] : 0.0f;
#pragma unroll
            for (int r = 0; r < 4; ++r) {
                float v = acc[m][n][r] + bv;
                if (RELU) v = fmaxf(v, 0.0f);
                if (OUTBF)
                    ((short*)Cout)[(size_t)(row + r) * N + col] = f2bf(v);
                else
                    ((float*)Cout)[(size_t)(row + r) * N + col] = v;
            }
        }
    }
}

// ---------------- flash attention (swapped QK^T, 32 q-rows/wave) ----------------
// grid (16, 32) = 512 blocks, 256 thr (4 waves x 32 q-rows = 128-row panel).
// S^T = mfma(K,Q): col=q=lane&15, keys in regs -> in-lane softmax (exp2 domain).
// O^T = mfma(Vt,P). V frags issued before softmax (latency hiding).
#define ATT_T 2048
#define ATT_QKS 3072
#define ATT_BT 4096

__global__ __launch_bounds__(256) void flash_attn(const short* __restrict__ Q,
                                                  const short* __restrict__ Km,
                                                  const short* __restrict__ Vt,
                                                  short* __restrict__ Oout) {
    // XCD-chunked swizzle: 4 consecutive (b,h) per XCD; heavy panels first.
    int flat = blockIdx.x + (blockIdx.y << 4);      // nwg = 512
    int w = ((flat & 7) << 6) + (flat >> 3);        // chunk = 64
    const int bh = w >> 4;
    const int b = bh >> 4;
    const int h = bh & 15;
    const int panel = 15 - (w & 15);                // heavy-first (LPT)
    const int wid = threadIdx.x >> 6;
    const int lane = threadIdx.x & 63;
    const int lr = lane & 15;
    const int g = lane >> 4;
    const int q0 = panel * 128 + wid * 32;

    __shared__ __align__(16) short Plds[4][2][16][72];

    // Q fragments (B-operand), 2 q-subtiles x 2 k-steps
    bf16x8 aq[2][2];
#pragma unroll
    for (int qs = 0; qs < 2; ++qs)
#pragma unroll
        for (int ds = 0; ds < 2; ++ds)
            aq[qs][ds] = *(const bf16x8*)(Q + (size_t)(b * ATT_T + q0 + qs * 16 + lr) * ATT_QKS +
                                          h * 64 + ds * 32 + g * 8);

    f32x4 O[2][4] = {};
    float mrun[2] = { -1e30f, -1e30f }, lrun[2] = { 0.0f, 0.0f };
    const int qrow[2] = { q0 + lr, q0 + 16 + lr };
    const float SC = 0.125f * 1.44269504f;  // scale * log2(e): softmax in exp2 domain

    const int nkv = ((q0 + 31) >> 6) + 1;
    for (int kb = 0; kb < nkv; ++kb) {
        const int k0 = kb * 64;
        // K fragments
        bf16x8 kf[4][2];
#pragma unroll
        for (int t = 0; t < 4; ++t) {
            const size_t krow = (size_t)(b * ATT_T + k0 + 16 * t + lr) * ATT_QKS + h * 64;
            kf[t][0] = *(const bf16x8*)(Km + krow + g * 8);
            kf[t][1] = *(const bf16x8*)(Km + krow + 32 + g * 8);
        }
        // V fragments — issue NOW so global latency hides under softmax
        bf16x8 vf[4][2];
#pragma unroll
        for (int n = 0; n < 4; ++n)
#pragma unroll
            for (int ks = 0; ks < 2; ++ks)
                vf[n][ks] = *(const bf16x8*)(Vt + (size_t)(h * 64 + n * 16 + lr) * ATT_BT +
                                             b * ATT_T + k0 + ks * 32 + g * 8);
        // per-subtile S + online softmax (two independent chains)
#pragma unroll
        for (int qs = 0; qs < 2; ++qs) {
            f32x4 st[4];
#pragma unroll
            for (int t = 0; t < 4; ++t) {
                f32x4 s = {};
                s = __builtin_amdgcn_mfma_f32_16x16x32_bf16(kf[t][0], aq[qs][0], s, 0, 0, 0);
                s = __builtin_amdgcn_mfma_f32_16x16x32_bf16(kf[t][1], aq[qs][1], s, 0, 0, 0);
                st[t] = s;
            }
            float v[4][4];
            float mx = -3e38f;
#pragma unroll
            for (int t = 0; t < 4; ++t)
#pragma unroll
                for (int r = 0; r < 4; ++r) {
                    float val = st[t][r] * SC;
                    if (k0 + 16 * t + g * 4 + r > qrow[qs]) val = -3e38f;
                    v[t][r] = val;
                    mx = fmaxf(mx, val);
                }
            mx = fmaxf(mx, __shfl_xor(mx, 16));
            mx = fmaxf(mx, __shfl_xor(mx, 32));
            const float mnew = fmaxf(mrun[qs], mx);
            const float alpha = exp2f(mrun[qs] - mnew);
            mrun[qs] = mnew;
            float rs = 0.0f;
#pragma unroll
            for (int t = 0; t < 4; ++t) {
                short4v pw;
#pragma unroll
                for (int r = 0; r < 4; ++r) {
                    float p = exp2f(v[t][r] - mnew);
                    rs += p;
                    pw[r] = f2bf(p);
                }
                *(short4v*)(&Plds[wid][qs][lr][16 * t + g * 4]) = pw;
            }
            rs += __shfl_xor(rs, 16);
            rs += __shfl_xor(rs, 32);
            lrun[qs] = lrun[qs] * alpha + rs;
#pragma unroll
            for (int n = 0; n < 4; ++n)
#pragma unroll
                for (int r = 0; r < 4; ++r) O[qs][n][r] *= alpha;
        }
        asm volatile("s_waitcnt lgkmcnt(0)" ::: "memory");
        __builtin_amdgcn_sched_barrier(0);
        // PV
#pragma unroll
        for (int qs = 0; qs < 2; ++qs)
#pragma unroll
            for (int ks = 0; ks < 2; ++ks) {
                bf16x8 pf = *(const bf16x8*)(&Plds[wid][qs][lr][ks * 32 + g * 8]);
#pragma unroll
                for (int n = 0; n < 4; ++n)
                    O[qs][n] = __builtin_amdgcn_mfma_f32_16x16x32_bf16(vf[n][ks], pf, O[qs][n], 0, 0, 0);
            }
        asm volatile("s_waitcnt lgkmcnt(0)" ::: "memory");
        __builtin_amdgcn_sched_barrier(0);
    }
#pragma unroll
    for (int qs = 0; qs < 2; ++qs) {
        const float inv = 1.0f / lrun[qs];
#pragma unroll
        for (int n = 0; n < 4; ++n) {
            short4v ov;
#pragma unroll
            for (int r = 0; r < 4; ++r) ov[r] = f2bf(O[qs][n][r] * inv);
            *(short4v*)(Oout + (size_t)(b * ATT_T + q0 + qs * 16 + lr) * 1024 +
                        h * 64 + n * 16 + g * 4) = ov;
        }
    }
}

// ---------------- residual + layernorm ----------------
__global__ __launch_bounds__(256) void resid_ln(const float* __restrict__ x,
                                                const float* __restrict__ y,
                                                const float* __restrict__ g,
                                                const float* __restrict__ be,
                                                float* __restrict__ of,
                                                short* __restrict__ ob) {
    const int row = blockIdx.x;
    const int tid = threadIdx.x;
    const size_t base = (size_t)row * 1024 + tid * 4;
    float4 xv = *(const float4*)(x + base);
    float4 yv = *(const float4*)(y + base);
    float h0 = xv.x + yv.x, h1 = xv.y + yv.y, h2 = xv.z + yv.z, h3 = xv.w + yv.w;
    float s = h0 + h1 + h2 + h3;
    float ss = h0 * h0 + h1 * h1 + h2 * h2 + h3 * h3;
#pragma unroll
    for (int d = 1; d < 64; d <<= 1) {
        s += __shfl_xor(s, d);
        ss += __shfl_xor(ss, d);
    }
    __shared__ float as_[4], ass_[4];
    if ((tid & 63) == 0) { as_[tid >> 6] = s; ass_[tid >> 6] = ss; }
    __syncthreads();
    s = as_[0] + as_[1] + as_[2] + as_[3];
    ss = ass_[0] + ass_[1] + ass_[2] + ass_[3];
    const float mu = s * (1.0f / 1024.0f);
    const float var = ss * (1.0f / 1024.0f) - mu * mu;
    const float rstd = rsqrtf(var + 1e-5f);
    float4 gv = *(const float4*)(g + tid * 4);
    float4 bv = *(const float4*)(be + tid * 4);
    float o0 = (h0 - mu) * rstd * gv.x + bv.x;
    float o1 = (h1 - mu) * rstd * gv.y + bv.y;
    float o2 = (h2 - mu) * rstd * gv.z + bv.z;
    float o3 = (h3 - mu) * rstd * gv.w + bv.w;
    float4 ov = { o0, o1, o2, o3 };
    *(float4*)(of + base) = ov;
    if (ob) {
        short4v obv = { f2bf(o0), f2bf(o1), f2bf(o2), f2bf(o3) };
        *(short4v*)(ob + base) = obv;
    }
}

// ---------------- launch ----------------

extern "C" void kernel_launch(void* const* d_in, const int* in_sizes, int n_in,
                              void* d_out, int out_size, void* d_ws, size_t ws_size,
                              hipStream_t stream) {
    const float* x = (const float*)d_in[0];
    const float* wq = (const float*)d_in[1];
    const float* wk = (const float*)d_in[2];
    const float* wv = (const float*)d_in[3];
    const float* wp = (const float*)d_in[4];
    const float* bproj = (const float*)d_in[5];
    const float* w1 = (const float*)d_in[6];
    const float* b1 = (const float*)d_in[7];
    const float* w2 = (const float*)d_in[8];
    const float* b2 = (const float*)d_in[9];
    const float* g1 = (const float*)d_in[10];
    const float* be1 = (const float*)d_in[11];
    const float* g2 = (const float*)d_in[12];
    const float* be2 = (const float*)d_in[13];

    char* ws = (char*)d_ws;
    const size_t MB = 1024 * 1024;
    short* x_bf = (short*)(ws + 0);        // 8 MB  [4096][1024]
    short* wqkvT = (short*)(ws + 8 * MB);  // 6 MB  [3072][1024]
    short* wqT = wqkvT;
    short* wkT = (short*)(ws + 10 * MB);
    short* wvT = (short*)(ws + 12 * MB);
    short* wpT = (short*)(ws + 14 * MB);   // 2 MB
    short* w1T = (short*)(ws + 16 * MB);   // 8 MB
    short* w2T = (short*)(ws + 24 * MB);   // 8 MB
    short* qkv = (short*)(ws + 32 * MB);   // 24 MB [4096][3072]
    short* Vt  = (short*)(ws + 56 * MB);   // 8 MB  [1024][4096]
    short* hbf = (short*)(ws + 32 * MB);   // 32 MB (reuses qkv+Vt)
    short* attn = (short*)(ws + 64 * MB);  // 8 MB
    short* x1bf = (short*)(ws + 64 * MB);  // 8 MB (reuses attn)
    float* y1 = (float*)(ws + 72 * MB);    // 16 MB
    float* y2 = (float*)(ws + 72 * MB);    // 16 MB (reuses y1)
    float* x1f = (float*)(ws + 88 * MB);   // 16 MB

    dim3 blk(256);
    dim3 tb(32, 8);

    convert_f2b<<<dim3(4096), blk, 0, stream>>>(x, x_bf, 4096 * 1024 / 4);
    transpose_f2b<<<dim3(32, 32), tb, 0, stream>>>(wq, wqT, 1024, 1024);
    transpose_f2b<<<dim3(32, 32), tb, 0, stream>>>(wk, wkT, 1024, 1024);
    transpose_f2b<<<dim3(32, 32), tb, 0, stream>>>(wv, wvT, 1024, 1024);
    transpose_f2b<<<dim3(32, 32), tb, 0, stream>>>(wp, wpT, 1024, 1024);
    transpose_f2b<<<dim3(128, 32), tb, 0, stream>>>(w1, w1T, 1024, 4096);
    transpose_f2b<<<dim3(32, 128), tb, 0, stream>>>(w2, w2T, 4096, 1024);

    gemm_bt<128, 0, 0, 1><<<dim3(32, 24), blk, 0, stream>>>(x_bf, wqkvT, nullptr, qkv, 4096, 3072, 1024);
    transpose_b2b<<<dim3(32, 128), tb, 0, stream>>>(qkv + 2048, Vt, 4096, 1024, 3072);
    flash_attn<<<dim3(16, 32), blk, 0, stream>>>(qkv, qkv + 1024, Vt, attn);
    gemm_bt<64, 1, 0, 0><<<dim3(32, 16), blk, 0, stream>>>(attn, wpT, bproj, y1, 4096, 1024, 1024);
    resid_ln<<<dim3(4096), blk, 0, stream>>>(x, y1, g1, be1, x1f, x1bf);
    gemm_bt<128, 1, 1, 1><<<dim3(32, 32), blk, 0, stream>>>(x1bf, w1T, b1, hbf, 4096, 4096, 1024);
    gemm_bt<64, 1, 0, 0><<<dim3(32, 16), blk, 0, stream>>>(hbf, w2T, b2, y2, 4096, 1024, 4096);
    resid_ln<<<dim3(4096), blk, 0, stream>>>(x1f, y2, g2, be2, (float*)d_out, nullptr);
}